// Round 13
// baseline (1951.002 us; speedup 1.0000x reference)
//
#include <hip/hip_runtime.h>
#include <math.h>

// Problem constants
#define N_PTS   30000
#define DIM     64
#define K_C     500
#define K_PAD   512            // padded centroid columns (cols 500-511: zero/INF)
#define N_ITERS 1000

#define TM    128
#define NTM   235              // ceil(30000/128)
#define GRID  NTM              // 1 block/CU (160KB LDS); 235 <= 256 CUs -> all resident
#define BLK   1024             // 16 waves/CU = 4 waves/SIMD (latency hiding)

#define FPSCALE 262144.0f      // 2^18; int64 accumulate: exact, order-free
#define INV_FPSCALE (1.0 / 262144.0)

#define BAR_STRIDE 32
#define BAR_REL_OFF (GRID * BAR_STRIDE)

// scratch slot i -> index inside Bs (pad cols 500..511), i < 768
__device__ __forceinline__ int SLOT(int i) { return (i / 12) * K_PAD + 500 + (i % 12); }
#define MLS(i)  SLOT(i)        // move list [128]: pl | (old+1)<<7 | new<<16
#define CNT_ML  SLOT(128)

// ---------------------------------------------------------------------------
// Grid barrier (HW-validated rounds 2-12). Parallel release-stores on arrival,
// RELAXED polling (no per-poll L2 invalidate), single acquire fence after.
__device__ __forceinline__ void gridbar(int* bar, int n) {
  __syncthreads();
  if (blockIdx.x == 0) {
    const int t = threadIdx.x;
    if (t >= 1 && t < GRID) {
      while (__hip_atomic_load(&bar[t * BAR_STRIDE], __ATOMIC_RELAXED,
                               __HIP_MEMORY_SCOPE_AGENT) < n)
        __builtin_amdgcn_s_sleep(2);
      __builtin_amdgcn_fence(__ATOMIC_ACQUIRE, "agent");
    }
    __syncthreads();
    if (t == 0)
      __hip_atomic_store(&bar[BAR_REL_OFF], n, __ATOMIC_RELEASE,
                         __HIP_MEMORY_SCOPE_AGENT);
  } else {
    if (threadIdx.x == 0) {
      __hip_atomic_store(&bar[blockIdx.x * BAR_STRIDE], n, __ATOMIC_RELEASE,
                         __HIP_MEMORY_SCOPE_AGENT);
      while (__hip_atomic_load(&bar[BAR_REL_OFF], __ATOMIC_RELAXED,
                               __HIP_MEMORY_SCOPE_AGENT) < n)
        __builtin_amdgcn_s_sleep(2);
      __builtin_amdgcn_fence(__ATOMIC_ACQUIRE, "agent");
    }
    __syncthreads();
  }
}

// ---------------------------------------------------------------------------
// STATIC 160 KiB LDS: rounds 10-12 proved that with dynamic (extern) smem the
// compiler assumes 0 LDS -> targets 8 waves/SIMD -> caps VGPR at 64 and cannot
// software-pipeline the d-loop (all reg attrs ignored). Static allocation makes
// the 1-block/CU occupancy compile-time visible -> 4 waves/SIMD -> 128-VGPR
// budget -> accumulator in arch VGPRs + pipelined ds_reads.
__global__ __launch_bounds__(BLK)
void k_persist(const float* __restrict__ embeds,
               const float* __restrict__ cents0,  // [K_C][64] initial
               float* __restrict__ esq,           // [N_PTS]
               int* __restrict__ idx,             // [N_PTS] init -1
               int* __restrict__ gcnt,            // [K_C] persistent, init 0
               unsigned long long* __restrict__ acc,  // [K_C][64] int64, init 0
               int* mov,                          // [K_PAD] last-dirty iter tag, init -1
               float* __restrict__ csq_g,         // [K_PAD]
               int* __restrict__ changed,         // [N_ITERS] init 0
               int* __restrict__ bar,             // init 0
               float* __restrict__ out) {
  __shared__ __align__(16) float As[DIM * TM];     // 32 KB, staged ONCE
  __shared__ __align__(16) float Bs[DIM * K_PAD];  // 128 KB, persistent
  int* BsI = (int*)Bs;
  const int tid = threadIdx.x;
  const int bid = blockIdx.x;
  int bno = 0;

  // ---- pre-phase: esq ----
  {
    const int w = bid * 16 + (tid >> 6), d = tid & 63;
    for (int p = w; p < N_PTS; p += GRID * 16) {
      float v = embeds[(size_t)p * DIM + d];
      float s = v * v;
      #pragma unroll
      for (int m = 1; m < 64; m <<= 1) s += __shfl_xor(s, m, 64);
      if (d == 0) esq[p] = s;
    }
  }
  gridbar(bar, ++bno);

  const int m0 = bid * TM;
  const int tx = tid & 63, ty = tid >> 6;   // 64 col-lanes x 16 row-waves

  // ---- stage As ONCE (embeds loop-invariant; never clobbered) ----
  #pragma unroll
  for (int l = 0; l < 2; ++l) {
    int e = tid + l * BLK;          // 0..2047
    int pl = e & 127, d4 = e >> 7;
    int p = m0 + pl;
    float4 v = make_float4(0.f, 0.f, 0.f, 0.f);
    if (p < N_PTS) v = *reinterpret_cast<const float4*>(embeds + (size_t)p * DIM + d4 * 4);
    As[(d4 * 4 + 0) * TM + pl] = v.x; As[(d4 * 4 + 1) * TM + pl] = v.y;
    As[(d4 * 4 + 2) * TM + pl] = v.z; As[(d4 * 4 + 3) * TM + pl] = v.w;
  }
  float esq_r[8];
  #pragma unroll
  for (int i = 0; i < 8; ++i) {
    int p = m0 + ty * 8 + i;
    esq_r[i] = (p < N_PTS) ? esq[p] : 0.f;
  }

  // ---- main loop: ONE grid barrier per iteration ----
  // Timing assumption (empirically exact rounds 8-12): staging reads acc/gcnt
  // at iteration start while other blocks' delta_accum of the same iteration
  // finishes; work-balanced blocks make the skew << GEMM duration. State stays
  // exact regardless; convergence (no moves -> no writes) certifies the
  // fixed point race-free.
  for (int it = 0; it < N_ITERS; ++it) {
    if (tid == 0) BsI[CNT_ML] = 0;

    // ---- stage Bs columns (dirty-only for it>=2; bit-identical formula) ----
    if (tid < K_PAD) {
      bool doStage;
      if (it == 0)      doStage = true;
      else if (it == 1) doStage = (tid < K_C);
      else              doStage = (tid < K_C) && (mov[tid] >= it - 1);
      if (doStage) {
        float s4[16];
        if (it == 0) {
          if (tid < K_C) {
            #pragma unroll
            for (int l = 0; l < 16; ++l) {
              float4 v = *reinterpret_cast<const float4*>(cents0 + (size_t)tid * DIM + l * 4);
              Bs[(l * 4 + 0) * K_PAD + tid] = v.x; Bs[(l * 4 + 1) * K_PAD + tid] = v.y;
              Bs[(l * 4 + 2) * K_PAD + tid] = v.z; Bs[(l * 4 + 3) * K_PAD + tid] = v.w;
              s4[l] = (v.x * v.x + v.y * v.y) + (v.z * v.z + v.w * v.w);
            }
          } else {  // pad columns: zeros + INF csq, staged once, clean forever
            #pragma unroll
            for (int l = 0; l < 16; ++l) {
              Bs[(l * 4 + 0) * K_PAD + tid] = 0.f; Bs[(l * 4 + 1) * K_PAD + tid] = 0.f;
              Bs[(l * 4 + 2) * K_PAD + tid] = 0.f; Bs[(l * 4 + 3) * K_PAD + tid] = 0.f;
              s4[l] = 0.f;
            }
          }
        } else {
          // EXACT update formula: (float)((double)acc * 2^-18) / (count + 1e-6f)
          float fc = (float)gcnt[tid] + 1e-6f;
          #pragma unroll
          for (int l = 0; l < 16; ++l) {
            const unsigned long long* ap = acc + (size_t)tid * DIM + l * 4;
            longlong2 a0 = *reinterpret_cast<const longlong2*>(ap);
            longlong2 a1 = *reinterpret_cast<const longlong2*>(ap + 2);
            float n0 = (float)((double)a0.x * INV_FPSCALE) / fc;
            float n1 = (float)((double)a0.y * INV_FPSCALE) / fc;
            float n2 = (float)((double)a1.x * INV_FPSCALE) / fc;
            float n3 = (float)((double)a1.y * INV_FPSCALE) / fc;
            Bs[(l * 4 + 0) * K_PAD + tid] = n0; Bs[(l * 4 + 1) * K_PAD + tid] = n1;
            Bs[(l * 4 + 2) * K_PAD + tid] = n2; Bs[(l * 4 + 3) * K_PAD + tid] = n3;
            s4[l] = (n0 * n0 + n1 * n1) + (n2 * n2 + n3 * n3);
          }
        }
        // csq: adjacent-pair tree == lane-0 chain of the original butterfly
        float s8[8], s16[4], s32[2];
        #pragma unroll
        for (int m = 0; m < 8; ++m) s8[m] = s4[2 * m] + s4[2 * m + 1];
        #pragma unroll
        for (int m = 0; m < 4; ++m) s16[m] = s8[2 * m] + s8[2 * m + 1];
        s32[0] = s16[0] + s16[1]; s32[1] = s16[2] + s16[3];
        float cs = s32[0] + s32[1];
        csq_g[tid] = (tid < K_C) ? cs : INFINITY;
      }
    }
    __syncthreads();

    // ---- d-loop: 8x8 register tile (A wave-broadcast, B conflict-free) ----
    float acc_r[8][8];
    #pragma unroll
    for (int i = 0; i < 8; ++i)
      #pragma unroll
      for (int j = 0; j < 8; ++j) acc_r[i][j] = 0.f;

    #pragma unroll 4
    for (int d = 0; d < DIM; ++d) {
      const float* ar = As + d * TM + ty * 8;
      float4 a0 = *reinterpret_cast<const float4*>(ar);
      float4 a1 = *reinterpret_cast<const float4*>(ar + 4);
      const float* br = Bs + d * K_PAD + tx * 4;
      float4 b0 = *reinterpret_cast<const float4*>(br);
      float4 b1 = *reinterpret_cast<const float4*>(br + 256);
      float av[8] = {a0.x, a0.y, a0.z, a0.w, a1.x, a1.y, a1.z, a1.w};
      float bv[8] = {b0.x, b0.y, b0.z, b0.w, b1.x, b1.y, b1.z, b1.w};
      #pragma unroll
      for (int i = 0; i < 8; ++i)
        #pragma unroll
        for (int j = 0; j < 8; ++j)
          acc_r[i][j] = fmaf(av[i], bv[j], acc_r[i][j]);
    }

    // ---- epilogue: distances + argmin (ascending n, strict '<') ----
    float4 c0 = *reinterpret_cast<const float4*>(csq_g + tx * 4);
    float4 c1 = *reinterpret_cast<const float4*>(csq_g + 256 + tx * 4);
    float cv[8] = {c0.x, c0.y, c0.z, c0.w, c1.x, c1.y, c1.z, c1.w};
    float best[8]; int bidx[8];
    #pragma unroll
    for (int i = 0; i < 8; ++i) { best[i] = INFINITY; bidx[i] = 0; }
    #pragma unroll
    for (int g = 0; g < 2; ++g) {
      #pragma unroll
      for (int j = 0; j < 4; ++j) {
        int c = g * 4 + j;
        int n = g * 256 + tx * 4 + j;
        #pragma unroll
        for (int i = 0; i < 8; ++i) {
          float dd = (esq_r[i] - 2.0f * acc_r[i][c]) + cv[c];
          if (dd < best[i]) { best[i] = dd; bidx[i] = n; }
        }
      }
    }

    // full-wave (64-lane) lexicographic argmin; lane 0 publishes
    #pragma unroll
    for (int i = 0; i < 8; ++i) {
      float v = best[i]; int bi = bidx[i];
      #pragma unroll
      for (int s = 1; s < 64; s <<= 1) {
        float ov = __shfl_xor(v, s, 64);
        int   oi = __shfl_xor(bi, s, 64);
        if (ov < v || (ov == v && oi < bi)) { v = ov; bi = oi; }
      }
      if (tx == 0) {
        int pl = ty * 8 + i, p = m0 + pl;
        if (p < N_PTS) {
          int old = idx[p];
          if (old != bi) {
            idx[p] = bi;
            int slot = atomicAdd(&BsI[CNT_ML], 1);
            BsI[MLS(slot)] = pl | ((old + 1) << 7) | (bi << 16);
            if (slot == 0)
              __hip_atomic_store(&changed[it], 1, __ATOMIC_RELAXED,
                                 __HIP_MEMORY_SCOPE_AGENT);
          }
        }
      }
    }
    __syncthreads();   // move list final

    // ---- delta accumulation: exact int64 +/-, order-free; mark dirty ----
    {
      const int w8 = tid >> 6, lane = tid & 63;
      const int cnt = BsI[CNT_ML];
      for (int i = w8; i < cnt; i += 16) {
        int e = BsI[MLS(i)];
        int pl = e & 127, old = ((e >> 7) & 511) - 1, k = e >> 16;
        float v = embeds[(size_t)(m0 + pl) * DIM + lane];
        long long iv = (long long)__float2int_rn(v * FPSCALE);
        atomicAdd(&acc[(size_t)k * DIM + lane], (unsigned long long)iv);
        if (old >= 0)
          atomicAdd(&acc[(size_t)old * DIM + lane], (unsigned long long)(-iv));
        if (lane == 0) {
          atomicAdd(&gcnt[k], 1);
          __hip_atomic_store(&mov[k], it, __ATOMIC_RELAXED, __HIP_MEMORY_SCOPE_AGENT);
          if (old >= 0) {
            atomicAdd(&gcnt[old], -1);
            __hip_atomic_store(&mov[old], it, __ATOMIC_RELAXED, __HIP_MEMORY_SCOPE_AGENT);
          }
        }
      }
    }
    gridbar(bar, ++bno);

    // exact fixed point: no move => acc/gcnt unchanged => identity forever
    if (__hip_atomic_load(&changed[it], __ATOMIC_RELAXED,
                          __HIP_MEMORY_SCOPE_AGENT) == 0)
      break;
  }

  // ---- final output: [cents 32000][idx as f32 30000][counts 500] ----
  const int tot = K_C * DIM + N_PTS + K_C;
  for (int g = bid * BLK + tid; g < tot; g += GRID * BLK) {
    float v;
    if (g < K_C * DIM) {
      int k = g >> 6;
      v = (float)((double)(long long)acc[g] * INV_FPSCALE) / ((float)gcnt[k] + 1e-6f);
    } else if (g < K_C * DIM + N_PTS) {
      v = (float)idx[g - K_C * DIM];
    } else {
      v = (float)gcnt[g - K_C * DIM - N_PTS];
    }
    out[g] = v;
  }
}

// ---------------------------------------------------------------------------
extern "C" void kernel_launch(void* const* d_in, const int* in_sizes, int n_in,
                              void* d_out, int out_size, void* d_ws, size_t ws_size,
                              hipStream_t stream) {
  const float* embeds = (const float*)d_in[0];
  const float* init_c = (const float*)d_in[1];
  float* out = (float*)d_out;

  char* w = (char*)d_ws;
  size_t off = 0;
  auto alloc = [&](size_t bytes) -> void* {
    void* p = w + off;
    off += (bytes + 255) & ~(size_t)255;
    return p;
  };
  float* cents0 = (float*)alloc((size_t)K_C * DIM * sizeof(float));
  float* esq    = (float*)alloc((size_t)N_PTS * sizeof(float));
  int*   idx    = (int*)  alloc((size_t)N_PTS * sizeof(int));
  int*   gcnt   = (int*)  alloc((size_t)K_C * sizeof(int));
  unsigned long long* acc =
      (unsigned long long*)alloc((size_t)K_C * DIM * sizeof(unsigned long long));
  int*   mov    = (int*)  alloc((size_t)K_PAD * sizeof(int));
  float* csq_g  = (float*)alloc((size_t)K_PAD * sizeof(float));
  int*   chg    = (int*)  alloc((size_t)N_ITERS * sizeof(int));
  int*   bar    = (int*)  alloc((size_t)(BAR_REL_OFF + 64) * sizeof(int));

  hipMemcpyAsync(cents0, init_c, (size_t)K_C * DIM * sizeof(float),
                 hipMemcpyDeviceToDevice, stream);
  hipMemsetAsync(gcnt, 0, (size_t)K_C * sizeof(int), stream);
  hipMemsetAsync(acc, 0, (size_t)K_C * DIM * sizeof(unsigned long long), stream);
  hipMemsetAsync(idx, 0xFF, (size_t)N_PTS * sizeof(int), stream);   // -1: changed@it0
  hipMemsetAsync(mov, 0xFF, (size_t)K_PAD * sizeof(int), stream);   // -1: all clean
  hipMemsetAsync(chg, 0, (size_t)N_ITERS * sizeof(int), stream);
  hipMemsetAsync(bar, 0, (size_t)(BAR_REL_OFF + 64) * sizeof(int), stream);

  k_persist<<<dim3(GRID), dim3(BLK), 0, stream>>>(
      embeds, cents0, esq, idx, gcnt, acc, mov, csq_g, chg, bar, out);
}

// Round 14
// 1900.481 us; speedup vs baseline: 1.0266x; 1.0266x over previous
//
#include <hip/hip_runtime.h>
#include <math.h>

// Problem constants
#define N_PTS   30000
#define DIM     64
#define K_C     500
#define K_PAD   512            // padded centroid columns (cols 500-511: scratch/INF)
#define N_ITERS 1000

#define TM    128
#define NTM   235              // ceil(30000/128)
#define GRID  NTM              // 1 block/CU (160KB LDS); all resident
#define BLK   512              // 8 waves/CU: the config PROVEN to get 128 VGPRs

#define FPSCALE 262144.0f      // 2^18; int64 accumulate: exact, order-free
#define INV_FPSCALE (1.0 / 262144.0)

#define BAR_STRIDE 32
#define BAR_REL_OFF (GRID * BAR_STRIDE)

// scratch slot i -> index inside Bs (pad cols 500..511), i < 768
__device__ __forceinline__ int SLOT(int i) { return (i / 12) * K_PAD + 500 + (i % 12); }
#define MLS(i)  SLOT(i)        // move list [128]: pl | (old+1)<<7 | new<<16
#define CNT_ML  SLOT(128)

// ---------------------------------------------------------------------------
// Grid barrier (HW-validated rounds 2-13). Parallel release-stores on arrival,
// RELAXED polling (no per-poll L2 invalidate), single acquire fence after.
__device__ __forceinline__ void gridbar(int* bar, int n) {
  __syncthreads();
  if (blockIdx.x == 0) {
    const int t = threadIdx.x;
    if (t >= 1 && t < GRID) {
      while (__hip_atomic_load(&bar[t * BAR_STRIDE], __ATOMIC_RELAXED,
                               __HIP_MEMORY_SCOPE_AGENT) < n)
        __builtin_amdgcn_s_sleep(2);
      __builtin_amdgcn_fence(__ATOMIC_ACQUIRE, "agent");
    }
    __syncthreads();
    if (t == 0)
      __hip_atomic_store(&bar[BAR_REL_OFF], n, __ATOMIC_RELEASE,
                         __HIP_MEMORY_SCOPE_AGENT);
  } else {
    if (threadIdx.x == 0) {
      __hip_atomic_store(&bar[blockIdx.x * BAR_STRIDE], n, __ATOMIC_RELEASE,
                         __HIP_MEMORY_SCOPE_AGENT);
      while (__hip_atomic_load(&bar[BAR_REL_OFF], __ATOMIC_RELAXED,
                               __HIP_MEMORY_SCOPE_AGENT) < n)
        __builtin_amdgcn_s_sleep(2);
      __builtin_amdgcn_fence(__ATOMIC_ACQUIRE, "agent");
    }
    __syncthreads();
  }
}

// ---------------------------------------------------------------------------
// Structure: BLK=512 (proven 128-VGPR codegen) + two 256-col half-passes with
// an 8x8 acc (64 regs) so the d-loop can be HAND-PIPELINED: d+1's fragments
// load while d's FMAs issue. Rounds 8-13 all exhausted their register budget
// (no prefetch possible) -> lockstep DS/VALU alternation at ~50% each.
__global__ __launch_bounds__(BLK)
void k_persist(const float* __restrict__ embeds,
               const float* __restrict__ cents0,  // [K_C][64] initial
               float* __restrict__ esq,           // [N_PTS]
               int* __restrict__ idx,             // [N_PTS] init -1
               int* __restrict__ gcnt,            // [K_C] persistent, init 0
               unsigned long long* __restrict__ acc,  // [K_C][64] int64, init 0
               int* mov,                          // [K_PAD] last-dirty iter tag, init -1
               float* __restrict__ csq_g,         // [K_PAD]
               int* __restrict__ changed,         // [N_ITERS] init 0
               int* __restrict__ bar,             // init 0
               float* __restrict__ out) {
  __shared__ __align__(16) float As[DIM * TM];     // 32 KB, staged ONCE
  __shared__ __align__(16) float Bs[DIM * K_PAD];  // 128 KB, persistent
  int* BsI = (int*)Bs;
  const int tid = threadIdx.x;
  const int bid = blockIdx.x;
  int bno = 0;

  // ---- pre-phase: esq ----
  {
    const int w = bid * 8 + (tid >> 6), d = tid & 63;
    for (int p = w; p < N_PTS; p += GRID * 8) {
      float v = embeds[(size_t)p * DIM + d];
      float s = v * v;
      #pragma unroll
      for (int m = 1; m < 64; m <<= 1) s += __shfl_xor(s, m, 64);
      if (d == 0) esq[p] = s;
    }
  }
  gridbar(bar, ++bno);

  const int m0 = bid * TM;
  const int tx = tid & 31, ty = tid >> 5;   // 32 col-lanes x 16 row-groups

  // ---- stage As ONCE (embeds loop-invariant; never clobbered) ----
  #pragma unroll
  for (int l = 0; l < 4; ++l) {
    int e = tid + l * BLK;          // 0..2047
    int pl = e & 127, d4 = e >> 7;
    int p = m0 + pl;
    float4 v = make_float4(0.f, 0.f, 0.f, 0.f);
    if (p < N_PTS) v = *reinterpret_cast<const float4*>(embeds + (size_t)p * DIM + d4 * 4);
    As[(d4 * 4 + 0) * TM + pl] = v.x; As[(d4 * 4 + 1) * TM + pl] = v.y;
    As[(d4 * 4 + 2) * TM + pl] = v.z; As[(d4 * 4 + 3) * TM + pl] = v.w;
  }

  // ---- main loop: ONE grid barrier per iteration ----
  // Timing assumption (empirically exact rounds 8-13): staging reads acc/gcnt
  // at iteration start while other blocks' delta_accum of the same iteration
  // finishes; work-balanced blocks make skew << GEMM duration. State stays
  // exact regardless; convergence (no moves -> no writes) certifies the
  // fixed point race-free.
  for (int it = 0; it < N_ITERS; ++it) {
    if (tid == 0) BsI[CNT_ML] = 0;

    // ---- stage Bs columns (dirty-only for it>=2; bit-identical formula) ----
    {
      bool doStage;
      if (it == 0)      doStage = true;
      else if (it == 1) doStage = (tid < K_C);
      else              doStage = (tid < K_C) && (mov[tid] >= it - 1);
      if (doStage) {
        float s4[16];
        if (it == 0) {
          if (tid < K_C) {
            #pragma unroll
            for (int l = 0; l < 16; ++l) {
              float4 v = *reinterpret_cast<const float4*>(cents0 + (size_t)tid * DIM + l * 4);
              Bs[(l * 4 + 0) * K_PAD + tid] = v.x; Bs[(l * 4 + 1) * K_PAD + tid] = v.y;
              Bs[(l * 4 + 2) * K_PAD + tid] = v.z; Bs[(l * 4 + 3) * K_PAD + tid] = v.w;
              s4[l] = (v.x * v.x + v.y * v.y) + (v.z * v.z + v.w * v.w);
            }
          } else {  // pad columns: zeros + INF csq (scratch overwrites are benign:
                    // csq=+INF makes pad distances +INF, never selected)
            #pragma unroll
            for (int l = 0; l < 16; ++l) {
              Bs[(l * 4 + 0) * K_PAD + tid] = 0.f; Bs[(l * 4 + 1) * K_PAD + tid] = 0.f;
              Bs[(l * 4 + 2) * K_PAD + tid] = 0.f; Bs[(l * 4 + 3) * K_PAD + tid] = 0.f;
              s4[l] = 0.f;
            }
          }
        } else {
          // EXACT update formula: (float)((double)acc * 2^-18) / (count + 1e-6f)
          float fc = (float)gcnt[tid] + 1e-6f;
          #pragma unroll
          for (int l = 0; l < 16; ++l) {
            const unsigned long long* ap = acc + (size_t)tid * DIM + l * 4;
            longlong2 a0 = *reinterpret_cast<const longlong2*>(ap);
            longlong2 a1 = *reinterpret_cast<const longlong2*>(ap + 2);
            float n0 = (float)((double)a0.x * INV_FPSCALE) / fc;
            float n1 = (float)((double)a0.y * INV_FPSCALE) / fc;
            float n2 = (float)((double)a1.x * INV_FPSCALE) / fc;
            float n3 = (float)((double)a1.y * INV_FPSCALE) / fc;
            Bs[(l * 4 + 0) * K_PAD + tid] = n0; Bs[(l * 4 + 1) * K_PAD + tid] = n1;
            Bs[(l * 4 + 2) * K_PAD + tid] = n2; Bs[(l * 4 + 3) * K_PAD + tid] = n3;
            s4[l] = (n0 * n0 + n1 * n1) + (n2 * n2 + n3 * n3);
          }
        }
        // csq: adjacent-pair tree == lane-0 chain of the original butterfly
        float s8[8], s16[4], s32[2];
        #pragma unroll
        for (int m = 0; m < 8; ++m) s8[m] = s4[2 * m] + s4[2 * m + 1];
        #pragma unroll
        for (int m = 0; m < 4; ++m) s16[m] = s8[2 * m] + s8[2 * m + 1];
        s32[0] = s16[0] + s16[1]; s32[1] = s16[2] + s16[3];
        float cs = s32[0] + s32[1];
        csq_g[tid] = (tid < K_C) ? cs : INFINITY;
      }
    }
    __syncthreads();

    // ---- GEMM: two half-passes, 8x8 acc, HAND-PIPELINED d-loop ----
    float best[8]; int bidx[8];
    #pragma unroll
    for (int i = 0; i < 8; ++i) { best[i] = INFINITY; bidx[i] = 0; }

    #pragma unroll
    for (int h = 0; h < 2; ++h) {
      const float* ap = As + ty * 8;
      const float* bp = Bs + h * 256 + tx * 4;

      float acc_r[8][8];
      #pragma unroll
      for (int i = 0; i < 8; ++i)
        #pragma unroll
        for (int j = 0; j < 8; ++j) acc_r[i][j] = 0.f;

      // preload d = 0
      float4 a0 = *reinterpret_cast<const float4*>(ap);
      float4 a1 = *reinterpret_cast<const float4*>(ap + 4);
      float4 b0 = *reinterpret_cast<const float4*>(bp);
      float4 b1 = *reinterpret_cast<const float4*>(bp + 128);

      #pragma unroll 8
      for (int d = 0; d < DIM; ++d) {
        // prefetch d+1 BEFORE the FMA block (clamped read at d=63; unused)
        const int dn = (d + 1 < DIM) ? d + 1 : d;
        float4 na0 = *reinterpret_cast<const float4*>(ap + dn * TM);
        float4 na1 = *reinterpret_cast<const float4*>(ap + dn * TM + 4);
        float4 nb0 = *reinterpret_cast<const float4*>(bp + dn * K_PAD);
        float4 nb1 = *reinterpret_cast<const float4*>(bp + dn * K_PAD + 128);

        float av[8] = {a0.x, a0.y, a0.z, a0.w, a1.x, a1.y, a1.z, a1.w};
        float bv[8] = {b0.x, b0.y, b0.z, b0.w, b1.x, b1.y, b1.z, b1.w};
        #pragma unroll
        for (int i = 0; i < 8; ++i)
          #pragma unroll
          for (int j = 0; j < 8; ++j)
            acc_r[i][j] = fmaf(av[i], bv[j], acc_r[i][j]);

        a0 = na0; a1 = na1; b0 = nb0; b1 = nb1;
      }

      // per-half epilogue: distances + running argmin (ascending n, strict '<')
      float esq_h[8];
      #pragma unroll
      for (int i = 0; i < 8; ++i) {
        int p = m0 + ty * 8 + i;
        esq_h[i] = (p < N_PTS) ? esq[p] : 0.f;
      }
      const int nbase = h * 256;
      float4 c0 = *reinterpret_cast<const float4*>(csq_g + nbase + tx * 4);
      float4 c1 = *reinterpret_cast<const float4*>(csq_g + nbase + 128 + tx * 4);
      float cv[8] = {c0.x, c0.y, c0.z, c0.w, c1.x, c1.y, c1.z, c1.w};
      #pragma unroll
      for (int g = 0; g < 2; ++g) {
        #pragma unroll
        for (int j = 0; j < 4; ++j) {
          int c = g * 4 + j;
          int n = nbase + g * 128 + tx * 4 + j;
          #pragma unroll
          for (int i = 0; i < 8; ++i) {
            float dd = (esq_h[i] - 2.0f * acc_r[i][c]) + cv[c];
            if (dd < best[i]) { best[i] = dd; bidx[i] = n; }
          }
        }
      }
    }

    // cross-lane lexicographic argmin over the 32 tx lanes (same-ty half-wave)
    #pragma unroll
    for (int i = 0; i < 8; ++i) {
      float v = best[i]; int bi = bidx[i];
      #pragma unroll
      for (int s = 1; s < 32; s <<= 1) {
        float ov = __shfl_xor(v, s, 64);
        int   oi = __shfl_xor(bi, s, 64);
        if (ov < v || (ov == v && oi < bi)) { v = ov; bi = oi; }
      }
      if (tx == 0) {
        int pl = ty * 8 + i, p = m0 + pl;
        if (p < N_PTS) {
          int old = idx[p];
          if (old != bi) {
            idx[p] = bi;
            int slot = atomicAdd(&BsI[CNT_ML], 1);
            BsI[MLS(slot)] = pl | ((old + 1) << 7) | (bi << 16);
            if (slot == 0)
              __hip_atomic_store(&changed[it], 1, __ATOMIC_RELAXED,
                                 __HIP_MEMORY_SCOPE_AGENT);
          }
        }
      }
    }
    __syncthreads();   // move list final

    // ---- delta accumulation: exact int64 +/-, order-free; mark dirty ----
    {
      const int w8 = tid >> 6, lane = tid & 63;
      const int cnt = BsI[CNT_ML];
      for (int i = w8; i < cnt; i += 8) {
        int e = BsI[MLS(i)];
        int pl = e & 127, old = ((e >> 7) & 511) - 1, k = e >> 16;
        float v = embeds[(size_t)(m0 + pl) * DIM + lane];
        long long iv = (long long)__float2int_rn(v * FPSCALE);
        atomicAdd(&acc[(size_t)k * DIM + lane], (unsigned long long)iv);
        if (old >= 0)
          atomicAdd(&acc[(size_t)old * DIM + lane], (unsigned long long)(-iv));
        if (lane == 0) {
          atomicAdd(&gcnt[k], 1);
          __hip_atomic_store(&mov[k], it, __ATOMIC_RELAXED, __HIP_MEMORY_SCOPE_AGENT);
          if (old >= 0) {
            atomicAdd(&gcnt[old], -1);
            __hip_atomic_store(&mov[old], it, __ATOMIC_RELAXED, __HIP_MEMORY_SCOPE_AGENT);
          }
        }
      }
    }
    gridbar(bar, ++bno);

    // exact fixed point: no move => acc/gcnt unchanged => identity forever
    if (__hip_atomic_load(&changed[it], __ATOMIC_RELAXED,
                          __HIP_MEMORY_SCOPE_AGENT) == 0)
      break;
  }

  // ---- final output: [cents 32000][idx as f32 30000][counts 500] ----
  const int tot = K_C * DIM + N_PTS + K_C;
  for (int g = bid * BLK + tid; g < tot; g += GRID * BLK) {
    float v;
    if (g < K_C * DIM) {
      int k = g >> 6;
      v = (float)((double)(long long)acc[g] * INV_FPSCALE) / ((float)gcnt[k] + 1e-6f);
    } else if (g < K_C * DIM + N_PTS) {
      v = (float)idx[g - K_C * DIM];
    } else {
      v = (float)gcnt[g - K_C * DIM - N_PTS];
    }
    out[g] = v;
  }
}

// ---------------------------------------------------------------------------
extern "C" void kernel_launch(void* const* d_in, const int* in_sizes, int n_in,
                              void* d_out, int out_size, void* d_ws, size_t ws_size,
                              hipStream_t stream) {
  const float* embeds = (const float*)d_in[0];
  const float* init_c = (const float*)d_in[1];
  float* out = (float*)d_out;

  char* w = (char*)d_ws;
  size_t off = 0;
  auto alloc = [&](size_t bytes) -> void* {
    void* p = w + off;
    off += (bytes + 255) & ~(size_t)255;
    return p;
  };
  float* cents0 = (float*)alloc((size_t)K_C * DIM * sizeof(float));
  float* esq    = (float*)alloc((size_t)N_PTS * sizeof(float));
  int*   idx    = (int*)  alloc((size_t)N_PTS * sizeof(int));
  int*   gcnt   = (int*)  alloc((size_t)K_C * sizeof(int));
  unsigned long long* acc =
      (unsigned long long*)alloc((size_t)K_C * DIM * sizeof(unsigned long long));
  int*   mov    = (int*)  alloc((size_t)K_PAD * sizeof(int));
  float* csq_g  = (float*)alloc((size_t)K_PAD * sizeof(float));
  int*   chg    = (int*)  alloc((size_t)N_ITERS * sizeof(int));
  int*   bar    = (int*)  alloc((size_t)(BAR_REL_OFF + 64) * sizeof(int));

  hipMemcpyAsync(cents0, init_c, (size_t)K_C * DIM * sizeof(float),
                 hipMemcpyDeviceToDevice, stream);
  hipMemsetAsync(gcnt, 0, (size_t)K_C * sizeof(int), stream);
  hipMemsetAsync(acc, 0, (size_t)K_C * DIM * sizeof(unsigned long long), stream);
  hipMemsetAsync(idx, 0xFF, (size_t)N_PTS * sizeof(int), stream);   // -1: changed@it0
  hipMemsetAsync(mov, 0xFF, (size_t)K_PAD * sizeof(int), stream);   // -1: all clean
  hipMemsetAsync(chg, 0, (size_t)N_ITERS * sizeof(int), stream);
  hipMemsetAsync(bar, 0, (size_t)(BAR_REL_OFF + 64) * sizeof(int), stream);

  k_persist<<<dim3(GRID), dim3(BLK), 0, stream>>>(
      embeds, cents0, esq, idx, gcnt, acc, mov, csq_g, chg, bar, out);
}